// Round 4
// baseline (2079.542 us; speedup 1.0000x reference)
//
#include <hip/hip_runtime.h>
#include <hip/hip_fp16.h>

#define DIM     192
#define NHEADS  6
#define WSZ     7
#define SHIFT   3
#define TOK     49
#define HW      224
#define NWIN    8192

typedef _Float16 half_t;
typedef _Float16 half8 __attribute__((ext_vector_type(8)));
typedef float    f32x4 __attribute__((ext_vector_type(4)));

#define WQKV_HALFS  (6*96*192)      // 110592: [head][96 rows: q0-31,k32-63,v64-95][192 k] linear
#define WPROJ_HALFS (6*192*32)      // 36864:  [head][192 ch][32 k] linear

// ---------------- weight prep: fp32 -> f16, packed linear ----------------
__global__ __launch_bounds__(256) void prep_weights(const float* __restrict__ qkv_w,
                                                    const float* __restrict__ proj_w,
                                                    half_t* __restrict__ wp) {
  int e = blockIdx.x * 256 + threadIdx.x;
  if (e < WQKV_HALFS) {
    int h  = e / 18432;
    int r1 = e % 18432;
    int r  = r1 / 192;
    int kk = r1 % 192;
    int sect = r >> 5;
    int chl  = r & 31;
    wp[e] = (half_t)qkv_w[(sect*192 + h*32 + chl)*192 + kk];
  } else {
    int e2 = e - WQKV_HALFS;
    if (e2 < WPROJ_HALFS) {
      int h  = e2 / 6144;
      int rr = (e2 >> 5) % 192;
      int kl = e2 & 31;
      wp[WQKV_HALFS + e2] = (half_t)proj_w[rr*192 + h*32 + kl];
    }
  }
}

// ---------------- LDS layout (bytes), total 39936 -> 4 blocks/CU nominal ----------------
// phase 1: s_x [49][200] half = 19600 @ 0        (dead after A-frag reg read)
// phase 2: s_q  @     0 : [52][40] half = 4160
//          s_k  @  4160 : [52][40] half = 4160
//          s_vt @  8320 : [32][64] half = 4096   (V transposed, 16B-chunk XOR swizzle)
//          s_aoh@ 12416 : [52][40] half = 4160
//          s_p  @ 16576 : [64][72] half = 9216   (normalized P)
// phase 3: s_out @ 0 : [192][52] f32 = 39936 (overlay)
#define SMEM_BYTES 39936

__global__ __launch_bounds__(512, 6) void swin_attn(const float* __restrict__ x,
                                                    const float* __restrict__ qkv_b,
                                                    const float* __restrict__ proj_b,
                                                    const half_t* __restrict__ wp,
                                                    float* __restrict__ out) {
  __shared__ __align__(16) unsigned char smem[SMEM_BYTES];
  half_t* s_x   = (half_t*)smem;              // [49][200]
  half_t* s_q   = (half_t*)smem;              // [52][40]
  half_t* s_k   = (half_t*)(smem + 4160);
  half_t* s_vt  = (half_t*)(smem + 8320);     // [32][64]
  half_t* s_aoh = (half_t*)(smem + 12416);    // [52][40]
  half_t* s_p   = (half_t*)(smem + 16576);    // [64][72]
  float*  s_out = (float*)smem;               // [192][52]

  int bid = blockIdx.x;
  bid = (bid & 7) * 1024 + (bid >> 3);        // XCD-aware swizzle (8192 % 8 == 0)
  int b  = bid >> 10;
  int wh = (bid >> 5) & 31;
  int ww = bid & 31;

  int tid  = threadIdx.x;
  int wave = tid >> 6;
  int lane = tid & 63;
  int lg   = lane >> 4;     // k-group 0..3
  int lr   = lane & 15;     // row/col within tile
  int m    = wave & 3;      // M-tile 0..3
  int nhf  = wave >> 2;     // N-half 0..1
  int mrow0 = m << 4;

  const float* xb = x + (size_t)b * DIM * HW * HW;

  // ---- gather shifted window -> s_x (f16), strength-reduced indexing
  {
    int c = tid / 49;
    int r = tid - c * 49;
    for (int it = 0; it < 19; ++it) {
      if (c < 192) {
        int i = r / 7, j = r - i * 7;
        int hh = wh*WSZ + i + SHIFT; if (hh >= HW) hh -= HW;
        int w2 = ww*WSZ + j + SHIFT; if (w2 >= HW) w2 -= HW;
        s_x[r*200 + c] = (half_t)xb[(size_t)c*(HW*HW) + hh*HW + w2];
      }
      r += 22; c += 10;              // 512 = 10*49 + 22
      if (r >= 49) { r -= 49; ++c; }
    }
  }
  __syncthreads();

  // ---- A fragments to registers, once (each thread: one row, 48 halfs)
  const half8 HZ = {0,0,0,0,0,0,0,0};
  half8 afr[6];
  {
    int arow = mrow0 + lr;
    const half_t* ax = s_x + (arow > 48 ? 48 : arow)*200 + lg*8;
    #pragma unroll
    for (int kc = 0; kc < 3; ++kc)
      #pragma unroll
      for (int ks = 0; ks < 2; ++ks)
        afr[kc*2 + ks] = *(const half8*)(ax + kc*64 + ks*32);
    if (arow > 48) {
      #pragma unroll
      for (int u = 0; u < 6; ++u) afr[u] = HZ;
    }
  }
  __syncthreads();   // s_x dead; its space becomes q/k/vt/aoh

  f32x4 pacc[6];
  #pragma unroll
  for (int n = 0; n < 6; ++n) { pacc[n][0]=0.f; pacc[n][1]=0.f; pacc[n][2]=0.f; pacc[n][3]=0.f; }

  const float qscale = 0.17677669529663687f;   // 32^-0.5
  const half_t* wproj = wp + WQKV_HALFS;

  for (int h = 0; h < NHEADS; ++h) {
    // ---------- qkv GEMM: B-frags direct from global (L2-hot), A from regs. No barriers.
    f32x4 acc[3];
    #pragma unroll
    for (int n = 0; n < 3; ++n) { acc[n][0]=0.f; acc[n][1]=0.f; acc[n][2]=0.f; acc[n][3]=0.f; }
    {
      const half_t* wqh = wp + (size_t)h*18432 + ((nhf*3)*16 + lr)*192 + lg*8;
      #pragma unroll
      for (int kc = 0; kc < 3; ++kc) {
        half8 bfr[6];
        #pragma unroll
        for (int i = 0; i < 3; ++i)
          #pragma unroll
          for (int ks = 0; ks < 2; ++ks)
            bfr[i*2+ks] = *(const half8*)(wqh + i*3072 + kc*64 + ks*32);
        #pragma unroll
        for (int ks = 0; ks < 2; ++ks)
          #pragma unroll
          for (int i = 0; i < 3; ++i)
            acc[i] = __builtin_amdgcn_mfma_f32_16x16x32_f16(afr[kc*2+ks], bfr[i*2+ks], acc[i], 0, 0, 0);
      }
    }
    // ---------- epilogue: q,k row-major [tok][d]; v transposed+swizzled [d][tok]
    #pragma unroll
    for (int i = 0; i < 3; ++i) {
      int nt   = nhf*3 + i;
      int sect = nt >> 1;                 // 0=q 1=k 2=v
      int chl  = (nt & 1)*16 + lr;        // 0..31
      float bia = qkv_b[sect*192 + h*32 + chl];
      if (sect == 0) {
        #pragma unroll
        for (int jj = 0; jj < 4; ++jj) {
          int tok = mrow0 + lg*4 + jj;
          if (tok < 52) s_q[tok*40 + chl] = (half_t)((acc[i][jj] + bia) * qscale);
        }
      } else if (sect == 1) {
        #pragma unroll
        for (int jj = 0; jj < 4; ++jj) {
          int tok = mrow0 + lg*4 + jj;
          if (tok < 52) s_k[tok*40 + chl] = (half_t)(acc[i][jj] + bia);
        }
      } else {
        int tok0 = mrow0 + lg*4;
        union { half_t h4[4]; uint2 u; } pk2;
        #pragma unroll
        for (int jj = 0; jj < 4; ++jj) {
          int tok = tok0 + jj;
          float v = (tok < TOK) ? (acc[i][jj] + bia) : 0.f;   // zero pad tokens
          pk2.h4[jj] = (half_t)v;
        }
        int chunk = (tok0 >> 3) ^ (chl & 7);
        *(uint2*)(s_vt + chl*64 + chunk*8 + (tok0 & 7)) = pk2.u;
      }
    }
    __syncthreads();   // q/k/vt visible

    // ---------- QK^T + softmax: nh==0 waves only; P stored pre-normalized
    if (nhf == 0) {
      f32x4 sacc[4];
      #pragma unroll
      for (int n = 0; n < 4; ++n) { sacc[n][0]=0.f; sacc[n][1]=0.f; sacc[n][2]=0.f; sacc[n][3]=0.f; }
      half8 aq = *(const half8*)(s_q + (mrow0 + lr)*40 + lg*8);
      #pragma unroll
      for (int n = 0; n < 4; ++n) {
        half8 bf = *(const half8*)(s_k + (n*16 + lr)*40 + lg*8);
        sacc[n] = __builtin_amdgcn_mfma_f32_16x16x32_f16(aq, bf, sacc[n], 0, 0, 0);
      }
      if (lr >= 1) {                       // mask cols 49..63
        #pragma unroll
        for (int jj = 0; jj < 4; ++jj) sacc[3][jj] = -1e30f;
      }
      #pragma unroll
      for (int jj = 0; jj < 4; ++jj) {
        float mx = fmaxf(fmaxf(sacc[0][jj], sacc[1][jj]), fmaxf(sacc[2][jj], sacc[3][jj]));
        #pragma unroll
        for (int d = 1; d < 16; d <<= 1) mx = fmaxf(mx, __shfl_xor(mx, d));
        float p[4], ssum = 0.f;
        #pragma unroll
        for (int n = 0; n < 4; ++n) { p[n] = __expf(sacc[n][jj] - mx); ssum += p[n]; }
        #pragma unroll
        for (int d = 1; d < 16; d <<= 1) ssum += __shfl_xor(ssum, d);
        float rl = 1.f / ssum;
        int tok = mrow0 + lg*4 + jj;
        if (tok < 52) {
          #pragma unroll
          for (int n = 0; n < 4; ++n)
            s_p[tok*72 + n*16 + lr] = (half_t)(p[n] * rl);
        }
      }
    }
    __syncthreads();   // P visible

    // ---------- PV: wave's d-tile (d = nhf*16+lr), K=64 toks in 2 steps
    f32x4 oacc;
    oacc[0]=0.f; oacc[1]=0.f; oacc[2]=0.f; oacc[3]=0.f;
    #pragma unroll
    for (int ks = 0; ks < 2; ++ks) {
      half8 a = *(const half8*)(s_p + (mrow0 + lr)*72 + ks*32 + lg*8);
      int d = nhf*16 + lr;
      int chunk = (ks*4 + lg) ^ (d & 7);
      half8 bf = *(const half8*)(s_vt + d*64 + chunk*8);
      oacc = __builtin_amdgcn_mfma_f32_16x16x32_f16(a, bf, oacc, 0, 0, 0);
    }
    #pragma unroll
    for (int jj = 0; jj < 4; ++jj) {
      int tok = mrow0 + lg*4 + jj;
      if (tok < 52) s_aoh[tok*40 + nhf*16 + lr] = (half_t)oacc[jj];
    }
    __syncthreads();   // aoh visible

    // ---------- proj accumulate for this head: B frags direct from global (L2-hot)
    {
      half8 a = *(const half8*)(s_aoh + (mrow0 + lr)*40 + lg*8);
      const half_t* wph = wproj + ((size_t)h*192 + (nhf*6)*16 + lr)*32 + lg*8;
      #pragma unroll
      for (int i2 = 0; i2 < 6; ++i2) {
        half8 bf = *(const half8*)(wph + i2*512);
        pacc[i2] = __builtin_amdgcn_mfma_f32_16x16x32_f16(a, bf, pacc[i2], 0, 0, 0);
      }
    }
  }
  __syncthreads();   // last proj-acc aoh reads done before s_out overlay

  // ---------- bias + transpose to s_out [192][52] f32
  #pragma unroll
  for (int i2 = 0; i2 < 6; ++i2) {
    int ch = (nhf*6 + i2)*16 + lr;
    float bia = proj_b[ch];
    #pragma unroll
    for (int jj = 0; jj < 4; ++jj) {
      int tok = mrow0 + lg*4 + jj;
      if (tok < TOK) s_out[ch*52 + tok] = pacc[i2][jj] + bia;
    }
  }
  __syncthreads();

  // ---------- scatter with inverse roll, strength-reduced indexing
  float* ob = out + (size_t)b * DIM * HW * HW;
  {
    int c = tid / 49;
    int r = tid - c * 49;
    for (int it = 0; it < 19; ++it) {
      if (c < 192) {
        int i = r / 7, j = r - i * 7;
        int hh = wh*WSZ + i + SHIFT; if (hh >= HW) hh -= HW;
        int w2 = ww*WSZ + j + SHIFT; if (w2 >= HW) w2 -= HW;
        ob[(size_t)c*(HW*HW) + hh*HW + w2] = s_out[c*52 + r];
      }
      r += 22; c += 10;
      if (r >= 49) { r -= 49; ++c; }
    }
  }
}

extern "C" void kernel_launch(void* const* d_in, const int* in_sizes, int n_in,
                              void* d_out, int out_size, void* d_ws, size_t ws_size,
                              hipStream_t stream) {
  const float* x      = (const float*)d_in[0];
  const float* qkv_w  = (const float*)d_in[1];
  const float* qkv_b  = (const float*)d_in[2];
  const float* proj_w = (const float*)d_in[3];
  const float* proj_b = (const float*)d_in[4];
  half_t* wpk = (half_t*)d_ws;   // uses 294912 bytes of d_ws

  prep_weights<<<576, 256, 0, stream>>>(qkv_w, proj_w, wpk);
  swin_attn<<<NWIN, 512, 0, stream>>>(x, qkv_b, proj_b, wpk, (float*)d_out);
}

// Round 5
// 1397.332 us; speedup vs baseline: 1.4882x; 1.4882x over previous
//
#include <hip/hip_runtime.h>
#include <hip/hip_fp16.h>

#define DIM     192
#define NHEADS  6
#define WSZ     7
#define SHIFT   3
#define TOK     49
#define HW      224
#define NWIN    8192

typedef _Float16 half_t;
typedef _Float16 half8 __attribute__((ext_vector_type(8)));
typedef float    f32x4 __attribute__((ext_vector_type(4)));

#define WQKV_HALFS  (6*96*192)      // 110592: [head][96 rows: q0-31,k32-63,v64-95][192 k] linear
#define WPROJ_HALFS (6*192*32)      // 36864:  [head][192 ch][32 k] linear

// ---------------- weight prep: fp32 -> f16, packed linear ----------------
__global__ __launch_bounds__(256) void prep_weights(const float* __restrict__ qkv_w,
                                                    const float* __restrict__ proj_w,
                                                    half_t* __restrict__ wp) {
  int e = blockIdx.x * 256 + threadIdx.x;
  if (e < WQKV_HALFS) {
    int h  = e / 18432;
    int r1 = e % 18432;
    int r  = r1 / 192;
    int kk = r1 % 192;
    int sect = r >> 5;
    int chl  = r & 31;
    wp[e] = (half_t)qkv_w[(sect*192 + h*32 + chl)*192 + kk];
  } else {
    int e2 = e - WQKV_HALFS;
    if (e2 < WPROJ_HALFS) {
      int h  = e2 / 6144;
      int rr = (e2 >> 5) % 192;
      int kl = e2 & 31;
      wp[WQKV_HALFS + e2] = (half_t)proj_w[rr*192 + h*32 + kl];
    }
  }
}

// ---------------- LDS layout (bytes), total 39936 ----------------
// phase 1: s_x [49][200] half = 19600 @ 0        (dead after A-frag reg read)
// phase 2: s_q  @     0 : [52][40] half = 4160
//          s_k  @  4160 : [52][40] half = 4160
//          s_vt @  8320 : [32][64] half = 4096   (V transposed, 16B-chunk XOR swizzle)
//          s_aoh@ 12416 : [52][40] half = 4160
//          s_p  @ 16576 : [64][72] half = 9216   (normalized P)
// phase 3: s_out @ 0 : [192][52] f32 = 39936 (overlay)
#define SMEM_BYTES 39936

// NOTE: (512,6) forced unified-VGPR cap ~85 -> massive scratch spill (round 4:
// 4.4 GB/dispatch spill traffic, 2.6x regression). (512,4) = cap 128, spill-free.
__global__ __launch_bounds__(512, 4) void swin_attn(const float* __restrict__ x,
                                                    const float* __restrict__ qkv_b,
                                                    const float* __restrict__ proj_b,
                                                    const half_t* __restrict__ wp,
                                                    float* __restrict__ out) {
  __shared__ __align__(16) unsigned char smem[SMEM_BYTES];
  half_t* s_x   = (half_t*)smem;              // [49][200]
  half_t* s_q   = (half_t*)smem;              // [52][40]
  half_t* s_k   = (half_t*)(smem + 4160);
  half_t* s_vt  = (half_t*)(smem + 8320);     // [32][64]
  half_t* s_aoh = (half_t*)(smem + 12416);    // [52][40]
  half_t* s_p   = (half_t*)(smem + 16576);    // [64][72]
  float*  s_out = (float*)smem;               // [192][52]

  int bid = blockIdx.x;
  bid = (bid & 7) * 1024 + (bid >> 3);        // XCD-aware swizzle (8192 % 8 == 0)
  int b  = bid >> 10;
  int wh = (bid >> 5) & 31;
  int ww = bid & 31;

  int tid  = threadIdx.x;
  int wave = tid >> 6;
  int lane = tid & 63;
  int lg   = lane >> 4;     // k-group 0..3
  int lr   = lane & 15;     // row/col within tile
  int m    = wave & 3;      // M-tile 0..3
  int nhf  = wave >> 2;     // N-half 0..1
  int mrow0 = m << 4;

  const float* xb = x + (size_t)b * DIM * HW * HW;

  // ---- gather shifted window -> s_x (f16), strength-reduced indexing
  {
    int c = tid / 49;
    int r = tid - c * 49;
    for (int it = 0; it < 19; ++it) {
      if (c < 192) {
        int i = r / 7, j = r - i * 7;
        int hh = wh*WSZ + i + SHIFT; if (hh >= HW) hh -= HW;
        int w2 = ww*WSZ + j + SHIFT; if (w2 >= HW) w2 -= HW;
        s_x[r*200 + c] = (half_t)xb[(size_t)c*(HW*HW) + hh*HW + w2];
      }
      r += 22; c += 10;              // 512 = 10*49 + 22
      if (r >= 49) { r -= 49; ++c; }
    }
  }
  __syncthreads();

  // ---- A fragments to registers, once (each thread: one row, 48 halfs)
  const half8 HZ = {0,0,0,0,0,0,0,0};
  half8 afr[6];
  {
    int arow = mrow0 + lr;
    const half_t* ax = s_x + (arow > 48 ? 48 : arow)*200 + lg*8;
    #pragma unroll
    for (int kc = 0; kc < 3; ++kc)
      #pragma unroll
      for (int ks = 0; ks < 2; ++ks)
        afr[kc*2 + ks] = *(const half8*)(ax + kc*64 + ks*32);
    if (arow > 48) {
      #pragma unroll
      for (int u = 0; u < 6; ++u) afr[u] = HZ;
    }
  }
  __syncthreads();   // s_x dead; its space becomes q/k/vt/aoh

  f32x4 pacc[6];
  #pragma unroll
  for (int n = 0; n < 6; ++n) { pacc[n][0]=0.f; pacc[n][1]=0.f; pacc[n][2]=0.f; pacc[n][3]=0.f; }

  const float qscale = 0.17677669529663687f;   // 32^-0.5
  const half_t* wproj = wp + WQKV_HALFS;

  for (int h = 0; h < NHEADS; ++h) {
    // ---------- qkv GEMM: B-frags direct from global (L2-hot), A from regs. No barriers.
    f32x4 acc[3];
    #pragma unroll
    for (int n = 0; n < 3; ++n) { acc[n][0]=0.f; acc[n][1]=0.f; acc[n][2]=0.f; acc[n][3]=0.f; }
    {
      const half_t* wqh = wp + (size_t)h*18432 + ((nhf*3)*16 + lr)*192 + lg*8;
      #pragma unroll
      for (int kc = 0; kc < 3; ++kc) {
        half8 bfr[6];
        #pragma unroll
        for (int i = 0; i < 3; ++i)
          #pragma unroll
          for (int ks = 0; ks < 2; ++ks)
            bfr[i*2+ks] = *(const half8*)(wqh + i*3072 + kc*64 + ks*32);
        #pragma unroll
        for (int ks = 0; ks < 2; ++ks)
          #pragma unroll
          for (int i = 0; i < 3; ++i)
            acc[i] = __builtin_amdgcn_mfma_f32_16x16x32_f16(afr[kc*2+ks], bfr[i*2+ks], acc[i], 0, 0, 0);
      }
    }
    // ---------- epilogue: q,k row-major [tok][d]; v transposed+swizzled [d][tok]
    #pragma unroll
    for (int i = 0; i < 3; ++i) {
      int nt   = nhf*3 + i;
      int sect = nt >> 1;                 // 0=q 1=k 2=v
      int chl  = (nt & 1)*16 + lr;        // 0..31
      float bia = qkv_b[sect*192 + h*32 + chl];
      if (sect == 0) {
        #pragma unroll
        for (int jj = 0; jj < 4; ++jj) {
          int tok = mrow0 + lg*4 + jj;
          if (tok < 52) s_q[tok*40 + chl] = (half_t)((acc[i][jj] + bia) * qscale);
        }
      } else if (sect == 1) {
        #pragma unroll
        for (int jj = 0; jj < 4; ++jj) {
          int tok = mrow0 + lg*4 + jj;
          if (tok < 52) s_k[tok*40 + chl] = (half_t)(acc[i][jj] + bia);
        }
      } else {
        int tok0 = mrow0 + lg*4;
        union { half_t h4[4]; uint2 u; } pk2;
        #pragma unroll
        for (int jj = 0; jj < 4; ++jj) {
          int tok = tok0 + jj;
          float v = (tok < TOK) ? (acc[i][jj] + bia) : 0.f;   // zero pad tokens
          pk2.h4[jj] = (half_t)v;
        }
        int chunk = (tok0 >> 3) ^ (chl & 7);
        *(uint2*)(s_vt + chl*64 + chunk*8 + (tok0 & 7)) = pk2.u;
      }
    }
    __syncthreads();   // q/k/vt visible

    // ---------- QK^T + softmax: nh==0 waves only; P stored pre-normalized
    if (nhf == 0) {
      f32x4 sacc[4];
      #pragma unroll
      for (int n = 0; n < 4; ++n) { sacc[n][0]=0.f; sacc[n][1]=0.f; sacc[n][2]=0.f; sacc[n][3]=0.f; }
      half8 aq = *(const half8*)(s_q + (mrow0 + lr)*40 + lg*8);
      #pragma unroll
      for (int n = 0; n < 4; ++n) {
        half8 bf = *(const half8*)(s_k + (n*16 + lr)*40 + lg*8);
        sacc[n] = __builtin_amdgcn_mfma_f32_16x16x32_f16(aq, bf, sacc[n], 0, 0, 0);
      }
      if (lr >= 1) {                       // mask cols 49..63
        #pragma unroll
        for (int jj = 0; jj < 4; ++jj) sacc[3][jj] = -1e30f;
      }
      #pragma unroll
      for (int jj = 0; jj < 4; ++jj) {
        float mx = fmaxf(fmaxf(sacc[0][jj], sacc[1][jj]), fmaxf(sacc[2][jj], sacc[3][jj]));
        #pragma unroll
        for (int d = 1; d < 16; d <<= 1) mx = fmaxf(mx, __shfl_xor(mx, d));
        float p[4], ssum = 0.f;
        #pragma unroll
        for (int n = 0; n < 4; ++n) { p[n] = __expf(sacc[n][jj] - mx); ssum += p[n]; }
        #pragma unroll
        for (int d = 1; d < 16; d <<= 1) ssum += __shfl_xor(ssum, d);
        float rl = 1.f / ssum;
        int tok = mrow0 + lg*4 + jj;
        if (tok < 52) {
          #pragma unroll
          for (int n = 0; n < 4; ++n)
            s_p[tok*72 + n*16 + lr] = (half_t)(p[n] * rl);
        }
      }
    }
    __syncthreads();   // P visible

    // ---------- PV: wave's d-tile (d = nhf*16+lr), K=64 toks in 2 steps
    f32x4 oacc;
    oacc[0]=0.f; oacc[1]=0.f; oacc[2]=0.f; oacc[3]=0.f;
    #pragma unroll
    for (int ks = 0; ks < 2; ++ks) {
      half8 a = *(const half8*)(s_p + (mrow0 + lr)*72 + ks*32 + lg*8);
      int d = nhf*16 + lr;
      int chunk = (ks*4 + lg) ^ (d & 7);
      half8 bf = *(const half8*)(s_vt + d*64 + chunk*8);
      oacc = __builtin_amdgcn_mfma_f32_16x16x32_f16(a, bf, oacc, 0, 0, 0);
    }
    #pragma unroll
    for (int jj = 0; jj < 4; ++jj) {
      int tok = mrow0 + lg*4 + jj;
      if (tok < 52) s_aoh[tok*40 + nhf*16 + lr] = (half_t)oacc[jj];
    }
    __syncthreads();   // aoh visible

    // ---------- proj accumulate for this head: B frags direct from global (L2-hot)
    {
      half8 a = *(const half8*)(s_aoh + (mrow0 + lr)*40 + lg*8);
      const half_t* wph = wproj + ((size_t)h*192 + (nhf*6)*16 + lr)*32 + lg*8;
      #pragma unroll
      for (int i2 = 0; i2 < 6; ++i2) {
        half8 bf = *(const half8*)(wph + i2*512);
        pacc[i2] = __builtin_amdgcn_mfma_f32_16x16x32_f16(a, bf, pacc[i2], 0, 0, 0);
      }
    }
  }
  __syncthreads();   // last proj-acc aoh reads done before s_out overlay

  // ---------- bias + transpose to s_out [192][52] f32
  #pragma unroll
  for (int i2 = 0; i2 < 6; ++i2) {
    int ch = (nhf*6 + i2)*16 + lr;
    float bia = proj_b[ch];
    #pragma unroll
    for (int jj = 0; jj < 4; ++jj) {
      int tok = mrow0 + lg*4 + jj;
      if (tok < TOK) s_out[ch*52 + tok] = pacc[i2][jj] + bia;
    }
  }
  __syncthreads();

  // ---------- scatter with inverse roll, strength-reduced indexing
  float* ob = out + (size_t)b * DIM * HW * HW;
  {
    int c = tid / 49;
    int r = tid - c * 49;
    for (int it = 0; it < 19; ++it) {
      if (c < 192) {
        int i = r / 7, j = r - i * 7;
        int hh = wh*WSZ + i + SHIFT; if (hh >= HW) hh -= HW;
        int w2 = ww*WSZ + j + SHIFT; if (w2 >= HW) w2 -= HW;
        ob[(size_t)c*(HW*HW) + hh*HW + w2] = s_out[c*52 + r];
      }
      r += 22; c += 10;
      if (r >= 49) { r -= 49; ++c; }
    }
  }
}

extern "C" void kernel_launch(void* const* d_in, const int* in_sizes, int n_in,
                              void* d_out, int out_size, void* d_ws, size_t ws_size,
                              hipStream_t stream) {
  const float* x      = (const float*)d_in[0];
  const float* qkv_w  = (const float*)d_in[1];
  const float* qkv_b  = (const float*)d_in[2];
  const float* proj_w = (const float*)d_in[3];
  const float* proj_b = (const float*)d_in[4];
  half_t* wpk = (half_t*)d_ws;   // uses 294912 bytes of d_ws

  prep_weights<<<576, 256, 0, stream>>>(qkv_w, proj_w, wpk);
  swin_attn<<<NWIN, 512, 0, stream>>>(x, qkv_b, proj_b, wpk, (float*)d_out);
}

// Round 6
// 1385.120 us; speedup vs baseline: 1.5013x; 1.0088x over previous
//
#include <hip/hip_runtime.h>
#include <hip/hip_fp16.h>

#define DIM     192
#define NHEADS  6
#define WSZ     7
#define SHIFT   3
#define TOK     49
#define HW      224
#define NWIN    8192

typedef _Float16 half_t;
typedef _Float16 half8 __attribute__((ext_vector_type(8)));
typedef float    f32x4 __attribute__((ext_vector_type(4)));

#define WQKV_HALFS  (6*96*192)      // 110592: [head][96 rows: q0-31,k32-63,v64-95][192 k] linear
#define WPROJ_HALFS (6*192*32)      // 36864:  [head][192 ch][32 k] linear

// ---------------- weight prep: fp32 -> f16, packed linear ----------------
__global__ __launch_bounds__(256) void prep_weights(const float* __restrict__ qkv_w,
                                                    const float* __restrict__ proj_w,
                                                    half_t* __restrict__ wp) {
  int e = blockIdx.x * 256 + threadIdx.x;
  if (e < WQKV_HALFS) {
    int h  = e / 18432;
    int r1 = e % 18432;
    int r  = r1 / 192;
    int kk = r1 % 192;
    int sect = r >> 5;
    int chl  = r & 31;
    wp[e] = (half_t)qkv_w[(sect*192 + h*32 + chl)*192 + kk];
  } else {
    int e2 = e - WQKV_HALFS;
    if (e2 < WPROJ_HALFS) {
      int h  = e2 / 6144;
      int rr = (e2 >> 5) % 192;
      int kl = e2 & 31;
      wp[WQKV_HALFS + e2] = (half_t)proj_w[rr*192 + h*32 + kl];
    }
  }
}

// ---------------- LDS layout (bytes) ----------------
// phase 1: s_x [49][200] half = 19600 @ 0        (dead after A-frag reg read)
// phase 2: s_q  @     0 : [52][40] half = 4160
//          s_k  @  4160 : [52][40] half = 4160
//          s_vt @  8320 : [32][64] half = 4096   (V transposed, 16B-chunk XOR swizzle)
//          s_aoh@ 12416 : [52][40] half = 4160
//          s_p  @ 16576 : [64][72] half = 9216   (normalized P)
// phase 3: s_out @ 0 : [192][52] f32 = 39936 (overlay)
//
// SMEM padded 39936 -> 43008: CRITICAL. At 39936 B, 4 blocks/CU fit, and the
// register allocator spills to hit the 64-VGPR cap that occupancy implies
// (round 5: exactly 64 VGPR + 1.4 GB/dispatch scratch traffic, 1470 us).
// At 43008 B only 3 blocks/CU fit -> VGPR budget ~85 -> spill-free.
#define SMEM_BYTES 43008

__global__ __launch_bounds__(512, 4) void swin_attn(const float* __restrict__ x,
                                                    const float* __restrict__ qkv_b,
                                                    const float* __restrict__ proj_b,
                                                    const half_t* __restrict__ wp,
                                                    float* __restrict__ out) {
  __shared__ __align__(16) unsigned char smem[SMEM_BYTES];
  half_t* s_x   = (half_t*)smem;              // [49][200]
  half_t* s_q   = (half_t*)smem;              // [52][40]
  half_t* s_k   = (half_t*)(smem + 4160);
  half_t* s_vt  = (half_t*)(smem + 8320);     // [32][64]
  half_t* s_aoh = (half_t*)(smem + 12416);    // [52][40]
  half_t* s_p   = (half_t*)(smem + 16576);    // [64][72]
  float*  s_out = (float*)smem;               // [192][52]

  int bid = blockIdx.x;
  bid = (bid & 7) * 1024 + (bid >> 3);        // XCD-aware swizzle (8192 % 8 == 0)
  int b  = bid >> 10;
  int wh = (bid >> 5) & 31;
  int ww = bid & 31;

  int tid  = threadIdx.x;
  int wave = tid >> 6;
  int lane = tid & 63;
  int lg   = lane >> 4;     // k-group 0..3
  int lr   = lane & 15;     // row/col within tile
  int m    = wave & 3;      // M-tile 0..3
  int nhf  = wave >> 2;     // N-half 0..1
  int mrow0 = m << 4;

  const float* xb = x + (size_t)b * DIM * HW * HW;

  // ---- gather shifted window -> s_x (f16), strength-reduced indexing
  {
    int c = tid / 49;
    int r = tid - c * 49;
    for (int it = 0; it < 19; ++it) {
      if (c < 192) {
        int i = r / 7, j = r - i * 7;
        int hh = wh*WSZ + i + SHIFT; if (hh >= HW) hh -= HW;
        int w2 = ww*WSZ + j + SHIFT; if (w2 >= HW) w2 -= HW;
        s_x[r*200 + c] = (half_t)xb[(size_t)c*(HW*HW) + hh*HW + w2];
      }
      r += 22; c += 10;              // 512 = 10*49 + 22
      if (r >= 49) { r -= 49; ++c; }
    }
  }
  __syncthreads();

  // ---- A fragments to registers, once (each thread: one row, 48 halfs)
  const half8 HZ = {0,0,0,0,0,0,0,0};
  half8 afr[6];
  {
    int arow = mrow0 + lr;
    const half_t* ax = s_x + (arow > 48 ? 48 : arow)*200 + lg*8;
    #pragma unroll
    for (int kc = 0; kc < 3; ++kc)
      #pragma unroll
      for (int ks = 0; ks < 2; ++ks)
        afr[kc*2 + ks] = *(const half8*)(ax + kc*64 + ks*32);
    if (arow > 48) {
      #pragma unroll
      for (int u = 0; u < 6; ++u) afr[u] = HZ;
    }
  }
  __syncthreads();   // s_x dead; its space becomes q/k/vt/aoh

  f32x4 pacc[6];
  #pragma unroll
  for (int n = 0; n < 6; ++n) { pacc[n][0]=0.f; pacc[n][1]=0.f; pacc[n][2]=0.f; pacc[n][3]=0.f; }

  const float qscale = 0.17677669529663687f;   // 32^-0.5
  const half_t* wproj = wp + WQKV_HALFS;

  for (int h = 0; h < NHEADS; ++h) {
    // ---------- qkv GEMM: B-frags direct from global (L2-hot), A from regs. No barriers.
    f32x4 acc[3];
    #pragma unroll
    for (int n = 0; n < 3; ++n) { acc[n][0]=0.f; acc[n][1]=0.f; acc[n][2]=0.f; acc[n][3]=0.f; }
    {
      const half_t* wqh = wp + (size_t)h*18432 + ((nhf*3)*16 + lr)*192 + lg*8;
      #pragma unroll
      for (int kc = 0; kc < 3; ++kc) {
        half8 bfr[6];
        #pragma unroll
        for (int i = 0; i < 3; ++i)
          #pragma unroll
          for (int ks = 0; ks < 2; ++ks)
            bfr[i*2+ks] = *(const half8*)(wqh + i*3072 + kc*64 + ks*32);
        #pragma unroll
        for (int ks = 0; ks < 2; ++ks)
          #pragma unroll
          for (int i = 0; i < 3; ++i)
            acc[i] = __builtin_amdgcn_mfma_f32_16x16x32_f16(afr[kc*2+ks], bfr[i*2+ks], acc[i], 0, 0, 0);
      }
    }
    // ---------- epilogue: q,k row-major [tok][d]; v transposed+swizzled [d][tok]
    #pragma unroll
    for (int i = 0; i < 3; ++i) {
      int nt   = nhf*3 + i;
      int sect = nt >> 1;                 // 0=q 1=k 2=v
      int chl  = (nt & 1)*16 + lr;        // 0..31
      float bia = qkv_b[sect*192 + h*32 + chl];
      if (sect == 0) {
        #pragma unroll
        for (int jj = 0; jj < 4; ++jj) {
          int tok = mrow0 + lg*4 + jj;
          if (tok < 52) s_q[tok*40 + chl] = (half_t)((acc[i][jj] + bia) * qscale);
        }
      } else if (sect == 1) {
        #pragma unroll
        for (int jj = 0; jj < 4; ++jj) {
          int tok = mrow0 + lg*4 + jj;
          if (tok < 52) s_k[tok*40 + chl] = (half_t)(acc[i][jj] + bia);
        }
      } else {
        int tok0 = mrow0 + lg*4;
        union { half_t h4[4]; uint2 u; } pk2;
        #pragma unroll
        for (int jj = 0; jj < 4; ++jj) {
          int tok = tok0 + jj;
          float v = (tok < TOK) ? (acc[i][jj] + bia) : 0.f;   // zero pad tokens
          pk2.h4[jj] = (half_t)v;
        }
        int chunk = (tok0 >> 3) ^ (chl & 7);
        *(uint2*)(s_vt + chl*64 + chunk*8 + (tok0 & 7)) = pk2.u;
      }
    }
    __syncthreads();   // q/k/vt visible

    // ---------- QK^T + softmax: nh==0 waves only; P stored pre-normalized
    if (nhf == 0) {
      f32x4 sacc[4];
      #pragma unroll
      for (int n = 0; n < 4; ++n) { sacc[n][0]=0.f; sacc[n][1]=0.f; sacc[n][2]=0.f; sacc[n][3]=0.f; }
      half8 aq = *(const half8*)(s_q + (mrow0 + lr)*40 + lg*8);
      #pragma unroll
      for (int n = 0; n < 4; ++n) {
        half8 bf = *(const half8*)(s_k + (n*16 + lr)*40 + lg*8);
        sacc[n] = __builtin_amdgcn_mfma_f32_16x16x32_f16(aq, bf, sacc[n], 0, 0, 0);
      }
      if (lr >= 1) {                       // mask cols 49..63
        #pragma unroll
        for (int jj = 0; jj < 4; ++jj) sacc[3][jj] = -1e30f;
      }
      #pragma unroll
      for (int jj = 0; jj < 4; ++jj) {
        float mx = fmaxf(fmaxf(sacc[0][jj], sacc[1][jj]), fmaxf(sacc[2][jj], sacc[3][jj]));
        #pragma unroll
        for (int d = 1; d < 16; d <<= 1) mx = fmaxf(mx, __shfl_xor(mx, d));
        float p[4], ssum = 0.f;
        #pragma unroll
        for (int n = 0; n < 4; ++n) { p[n] = __expf(sacc[n][jj] - mx); ssum += p[n]; }
        #pragma unroll
        for (int d = 1; d < 16; d <<= 1) ssum += __shfl_xor(ssum, d);
        float rl = 1.f / ssum;
        int tok = mrow0 + lg*4 + jj;
        if (tok < 52) {
          #pragma unroll
          for (int n = 0; n < 4; ++n)
            s_p[tok*72 + n*16 + lr] = (half_t)(p[n] * rl);
        }
      }
    }
    __syncthreads();   // P visible

    // ---------- PV: wave's d-tile (d = nhf*16+lr), K=64 toks in 2 steps
    f32x4 oacc;
    oacc[0]=0.f; oacc[1]=0.f; oacc[2]=0.f; oacc[3]=0.f;
    #pragma unroll
    for (int ks = 0; ks < 2; ++ks) {
      half8 a = *(const half8*)(s_p + (mrow0 + lr)*72 + ks*32 + lg*8);
      int d = nhf*16 + lr;
      int chunk = (ks*4 + lg) ^ (d & 7);
      half8 bf = *(const half8*)(s_vt + d*64 + chunk*8);
      oacc = __builtin_amdgcn_mfma_f32_16x16x32_f16(a, bf, oacc, 0, 0, 0);
    }
    #pragma unroll
    for (int jj = 0; jj < 4; ++jj) {
      int tok = mrow0 + lg*4 + jj;
      if (tok < 52) s_aoh[tok*40 + nhf*16 + lr] = (half_t)oacc[jj];
    }
    __syncthreads();   // aoh visible

    // ---------- proj accumulate for this head: B frags direct from global (L2-hot)
    {
      half8 a = *(const half8*)(s_aoh + (mrow0 + lr)*40 + lg*8);
      const half_t* wph = wproj + ((size_t)h*192 + (nhf*6)*16 + lr)*32 + lg*8;
      #pragma unroll
      for (int i2 = 0; i2 < 6; ++i2) {
        half8 bf = *(const half8*)(wph + i2*512);
        pacc[i2] = __builtin_amdgcn_mfma_f32_16x16x32_f16(a, bf, pacc[i2], 0, 0, 0);
      }
    }
  }
  __syncthreads();   // last proj-acc aoh reads done before s_out overlay

  // ---------- bias + transpose to s_out [192][52] f32
  #pragma unroll
  for (int i2 = 0; i2 < 6; ++i2) {
    int ch = (nhf*6 + i2)*16 + lr;
    float bia = proj_b[ch];
    #pragma unroll
    for (int jj = 0; jj < 4; ++jj) {
      int tok = mrow0 + lg*4 + jj;
      if (tok < TOK) s_out[ch*52 + tok] = pacc[i2][jj] + bia;
    }
  }
  __syncthreads();

  // ---------- scatter with inverse roll, strength-reduced indexing
  float* ob = out + (size_t)b * DIM * HW * HW;
  {
    int c = tid / 49;
    int r = tid - c * 49;
    for (int it = 0; it < 19; ++it) {
      if (c < 192) {
        int i = r / 7, j = r - i * 7;
        int hh = wh*WSZ + i + SHIFT; if (hh >= HW) hh -= HW;
        int w2 = ww*WSZ + j + SHIFT; if (w2 >= HW) w2 -= HW;
        ob[(size_t)c*(HW*HW) + hh*HW + w2] = s_out[c*52 + r];
      }
      r += 22; c += 10;
      if (r >= 49) { r -= 49; ++c; }
    }
  }
}

extern "C" void kernel_launch(void* const* d_in, const int* in_sizes, int n_in,
                              void* d_out, int out_size, void* d_ws, size_t ws_size,
                              hipStream_t stream) {
  const float* x      = (const float*)d_in[0];
  const float* qkv_w  = (const float*)d_in[1];
  const float* qkv_b  = (const float*)d_in[2];
  const float* proj_w = (const float*)d_in[3];
  const float* proj_b = (const float*)d_in[4];
  half_t* wpk = (half_t*)d_ws;   // uses 294912 bytes of d_ws

  prep_weights<<<576, 256, 0, stream>>>(qkv_w, proj_w, wpk);
  swin_attn<<<NWIN, 512, 0, stream>>>(x, qkv_b, proj_b, wpk, (float*)d_out);
}